// Round 4
// baseline (244.425 us; speedup 1.0000x reference)
//
#include <hip/hip_runtime.h>

typedef unsigned short u16;
typedef unsigned int u32;
typedef __attribute__((ext_vector_type(8))) short short8;
typedef __attribute__((ext_vector_type(4))) float f32x4;

#define T_TOK 4096
#define DIM   1024
#define NEXP  16
#define INTER 512
#define NSH   1024
#define CAP   4096
#define BM 128
#define BN 64
#define BK 64

__device__ __forceinline__ u16 f2bf(float f) {
  union { float f; u32 u; } c; c.f = f;
  u32 u = c.u;
  return (u16)((u + 0x7FFFu + ((u >> 16) & 1u)) >> 16);
}

typedef __attribute__((address_space(1))) u32 u32_g;
typedef __attribute__((address_space(3))) u32 u32_l;
__device__ __forceinline__ void gload16(const u16* g, u16* l) {
  __builtin_amdgcn_global_load_lds((u32_g*)g, (u32_l*)l, 16, 0, 0);
}

// ---------------- fused gate: bf16-convert x + fp64 scores + softmax/top-k route ----------------
// 256 blocks x 512 threads; block owns 16 tokens.
__global__ void __launch_bounds__(512) k_gate2(const float* __restrict__ x,
                                               const float* __restrict__ gw,
                                               const float* __restrict__ gb,
                                               u16* __restrict__ xb,
                                               int* __restrict__ counts,
                                               int* __restrict__ bucket,
                                               float* __restrict__ tokw) {
  const int tid = threadIdx.x;
  const int blk = blockIdx.x;
  // phase 0: convert this block's 16x1024 chunk to bf16 (coalesced float4)
  {
    const float4* src = (const float4*)x + (size_t)blk * 4096;
    ushort4* dst = (ushort4*)xb + (size_t)blk * 4096;
#pragma unroll
    for (int i = 0; i < 8; ++i) {
      float4 v = src[i * 512 + tid];
      ushort4 o;
      o.x = f2bf(v.x); o.y = f2bf(v.y); o.z = f2bf(v.z); o.w = f2bf(v.w);
      dst[i * 512 + tid] = o;
    }
  }
  // phase 1: fp64 scores; thread = (h, tk, e)
  const int h  = tid >> 8;
  const int tk = (tid >> 4) & 15;
  const int e  = tid & 15;
  const int t  = blk * 16 + tk;
  const float* xr = x + (size_t)t * DIM + h * 512;
  const float* wr = gw + (size_t)e * DIM + h * 512;
  double p = 0.0;
#pragma unroll 8
  for (int i = 0; i < 128; ++i) {
    float4 xv = *reinterpret_cast<const float4*>(xr + i * 4);
    float4 wv = *reinterpret_cast<const float4*>(wr + i * 4);
    p += (double)xv.x * (double)wv.x;
    p += (double)xv.y * (double)wv.y;
    p += (double)xv.z * (double)wv.z;
    p += (double)xv.w * (double)wv.w;
  }
  __shared__ double part[512];
  __shared__ double sarr[16][16];
  part[tid] = p;
  __syncthreads();
  if (tid < 256) sarr[tk][e] = part[tid] + part[tid + 256];
  __syncthreads();
  // phase 2: one thread per token
  if (tid >= 16) return;
  const int tt = blk * 16 + tid;
  double s[NEXP];
#pragma unroll
  for (int q = 0; q < NEXP; ++q) s[q] = sarr[tid][q];
  double m = s[0];
#pragma unroll
  for (int q = 1; q < NEXP; ++q) m = s[q] > m ? s[q] : m;
  double ex[NEXP], sum = 0.0;
#pragma unroll
  for (int q = 0; q < NEXP; ++q) { ex[q] = exp(s[q] - m); sum += ex[q]; }
  double orig[NEXP], sc[NEXP];
#pragma unroll
  for (int q = 0; q < NEXP; ++q) { orig[q] = ex[q] / sum; sc[q] = orig[q] + (double)gb[q]; }
  double gs[4];
#pragma unroll
  for (int g = 0; g < 4; ++g) {
    double m1 = -1e300, m2 = -1e300;
#pragma unroll
    for (int j = 0; j < 4; ++j) {
      double v = sc[g * 4 + j];
      if (v > m1) { m2 = m1; m1 = v; } else if (v > m2) m2 = v;
    }
    gs[g] = m1 + m2;
  }
  int g1 = 0;
  for (int g = 1; g < 4; ++g) if (gs[g] > gs[g1]) g1 = g;
  int g2 = -1;
  for (int g = 0; g < 4; ++g) { if (g == g1) continue; if (g2 < 0 || gs[g] > gs[g2]) g2 = g; }
  int e1 = -1, e2 = -1;
  for (int q = 0; q < NEXP; ++q) {
    int g = q >> 2;
    if (g != g1 && g != g2) continue;
    if (e1 < 0 || sc[q] > sc[e1]) e1 = q;
  }
  for (int q = 0; q < NEXP; ++q) {
    int g = q >> 2;
    if ((g != g1 && g != g2) || q == e1) continue;
    if (e2 < 0 || sc[q] > sc[e2]) e2 = q;
  }
  tokw[2 * tt]     = (float)orig[e1];
  tokw[2 * tt + 1] = (float)orig[e2];
  int p0 = atomicAdd(&counts[e1], 1); bucket[e1 * CAP + p0] = 2 * tt;
  int p1 = atomicAdd(&counts[e2], 1); bucket[e2 * CAP + p1] = 2 * tt + 1;
}

// ---------------- fused transpose-convert, 1-D decoded over 6 jobs ----------------
struct TrJob { const float* src; u16* dst; int R, C, base; };
struct TrJobs { TrJob j[6]; };

__global__ void k_tr_all(TrJobs J) {
  const int id = blockIdx.x;
  int k = 0;
#pragma unroll
  for (int q = 1; q < 6; ++q) if (id >= J.j[q].base) k = q;
  const TrJob jb = J.j[k];
  const int rx = jb.C >> 5;
  const int per = rx * (jb.R >> 5);
  int rel = id - jb.base;
  const int b = rel / per; rel -= b * per;
  const int r0 = (rel / rx) << 5;
  const int c0 = (rel - (rel / rx) * rx) << 5;
  const float* src = jb.src + (size_t)b * jb.R * jb.C;
  u16* dst = jb.dst + (size_t)b * jb.R * jb.C;

  __shared__ float tile[32][33];
  const int tx = threadIdx.x, ty = threadIdx.y;
#pragma unroll
  for (int i = 0; i < 4; ++i)
    tile[ty + 8 * i][tx] = src[(size_t)(r0 + ty + 8 * i) * jb.C + c0 + tx];
  __syncthreads();
#pragma unroll
  for (int i = 0; i < 4; ++i)
    dst[(size_t)(c0 + ty + 8 * i) * jb.R + r0 + tx] = f2bf(tile[tx][ty + 8 * i]);
}

// ---------------- fused GEMM1 (z==0 shared | z>=1 routed): h = silu(.)*(.)  ----------------
// BM=128 BN=64 BK=64; 4 waves, wave w owns rows [w*32, w*32+32)
__global__ void __launch_bounds__(256, 4) k_g1(
    const u16* __restrict__ A, const u16* __restrict__ w1t, const u16* __restrict__ w3t,
    const u16* __restrict__ s1t, const u16* __restrict__ s3t,
    const float* __restrict__ be1, const float* __restrict__ be3,
    const float* __restrict__ bs1, const float* __restrict__ bs3,
    u16* __restrict__ hr, u16* __restrict__ hs,
    const int* __restrict__ counts, const int* __restrict__ bucket) {
  const int z = blockIdx.z;
  const bool sh = (z == 0);
  const int e = z - 1;
  const int N = sh ? NSH : INTER;
  const int nt = blockIdx.x;
  if (nt * BN >= N) return;
  const int M = sh ? T_TOK : counts[e];
  const int mt = blockIdx.y;
  if (mt * BM >= M) return;
  const int tid = threadIdx.x;
  const int lane = tid & 63, wid = tid >> 6;

  __shared__ __align__(16) u16 lA[BM * BK];
  __shared__ __align__(16) u16 lB1[BN * BK];
  __shared__ __align__(16) u16 lB3[BN * BK];

  const int srow = tid >> 3, sc16 = tid & 7;
  const int scsw = (sc16 ^ (srow & 7)) * 8;
  const int* bkt = bucket + e * CAP;
  const u16* B1 = sh ? s1t : w1t + (size_t)e * INTER * DIM;
  const u16* B3 = sh ? s3t : w3t + (size_t)e * INTER * DIM;

  const u16 *aptr[4], *b1ptr[2], *b3ptr[2];
#pragma unroll
  for (int p = 0; p < 4; ++p) {
    int r = mt * BM + srow + p * 32;
    size_t arow;
    if (sh) arow = (size_t)r;
    else { int pos = r < M ? r : M - 1; arow = (size_t)(bkt[pos] >> 1); }
    aptr[p] = A + arow * DIM + scsw;
  }
#pragma unroll
  for (int p = 0; p < 2; ++p) {
    size_t nrow = (size_t)(nt * BN + srow + p * 32);
    b1ptr[p] = B1 + nrow * DIM + scsw;
    b3ptr[p] = B3 + nrow * DIM + scsw;
  }

  f32x4 acc1[2][4], acc3[2][4];
#pragma unroll
  for (int i = 0; i < 2; ++i)
#pragma unroll
    for (int j = 0; j < 4; ++j) {
      acc1[i][j] = f32x4{0.f, 0.f, 0.f, 0.f};
      acc3[i][j] = f32x4{0.f, 0.f, 0.f, 0.f};
    }

  const int fr = lane & 15, fs = lane >> 4;
  const int csA = fr & 7;

  for (int kt = 0; kt < DIM; kt += BK) {
#pragma unroll
    for (int p = 0; p < 4; ++p)
      gload16(aptr[p] + kt, &lA[(srow + 32 * p) * BK + sc16 * 8]);
#pragma unroll
    for (int p = 0; p < 2; ++p) {
      int ldso = (srow + 32 * p) * BK + sc16 * 8;
      gload16(b1ptr[p] + kt, &lB1[ldso]);
      gload16(b3ptr[p] + kt, &lB3[ldso]);
    }
    __syncthreads();
#pragma unroll
    for (int kk = 0; kk < 2; ++kk) {
      const int c = ((kk * 4 + fs) ^ csA) * 8;
      short8 af[2];
#pragma unroll
      for (int mi = 0; mi < 2; ++mi)
        af[mi] = *reinterpret_cast<const short8*>(&lA[(wid * 32 + mi * 16 + fr) * BK + c]);
#pragma unroll
      for (int ni = 0; ni < 4; ++ni) {
        short8 b1f = *reinterpret_cast<const short8*>(&lB1[(ni * 16 + fr) * BK + c]);
        short8 b3f = *reinterpret_cast<const short8*>(&lB3[(ni * 16 + fr) * BK + c]);
#pragma unroll
        for (int mi = 0; mi < 2; ++mi) {
          acc1[mi][ni] = __builtin_amdgcn_mfma_f32_16x16x32_bf16(af[mi], b1f, acc1[mi][ni], 0, 0, 0);
          acc3[mi][ni] = __builtin_amdgcn_mfma_f32_16x16x32_bf16(af[mi], b3f, acc3[mi][ni], 0, 0, 0);
        }
      }
    }
    __syncthreads();
  }

  const float* bp1 = sh ? bs1 : be1 + (size_t)e * INTER;
  const float* bp3 = sh ? bs3 : be3 + (size_t)e * INTER;
#pragma unroll
  for (int mi = 0; mi < 2; ++mi) {
#pragma unroll
    for (int j = 0; j < 4; ++j) {
      int p = mt * BM + wid * 32 + mi * 16 + fs * 4 + j;
      if (p >= M) continue;
      u16* hp = sh ? hs + (size_t)p * NSH : hr + (size_t)bkt[p] * INTER;
#pragma unroll
      for (int ni = 0; ni < 4; ++ni) {
        int gcol = nt * BN + ni * 16 + fr;
        float v1 = acc1[mi][ni][j] + bp1[gcol];
        float v3 = acc3[mi][ni][j] + bp3[gcol];
        float hv = (v1 / (1.0f + __expf(-v1))) * v3;
        hp[gcol] = f2bf(hv);
      }
    }
  }
}

// ---------------- fused GEMM2, all paths atomicAdd into zeroed out ----------------
__global__ void __launch_bounds__(256, 4) k_g2(
    const u16* __restrict__ hr, const u16* __restrict__ hs,
    const u16* __restrict__ w2t, const u16* __restrict__ s2t,
    const float* __restrict__ be2, const float* __restrict__ bs2,
    float* __restrict__ out, const float* __restrict__ tokw,
    const int* __restrict__ counts, const int* __restrict__ bucket) {
  const int z = blockIdx.z;
  const bool sh = (z == 0);
  const int e = z - 1;
  const int K = sh ? NSH : INTER;
  const int M = sh ? T_TOK : counts[e];
  const int mt = blockIdx.y;
  if (mt * BM >= M) return;
  const int nt = blockIdx.x;
  const int tid = threadIdx.x;
  const int lane = tid & 63, wid = tid >> 6;

  __shared__ __align__(16) u16 lA[BM * BK];
  __shared__ __align__(16) u16 lB[BN * BK];

  const int srow = tid >> 3, sc16 = tid & 7;
  const int scsw = (sc16 ^ (srow & 7)) * 8;
  const int* bkt = bucket + e * CAP;
  const u16* Ab = sh ? hs : hr;
  const u16* Bb = sh ? s2t : w2t + (size_t)e * DIM * INTER;

  const u16 *aptr[4], *bptr[2];
#pragma unroll
  for (int p = 0; p < 4; ++p) {
    int r = mt * BM + srow + p * 32;
    size_t arow;
    if (sh) arow = (size_t)r;
    else { int pos = r < M ? r : M - 1; arow = (size_t)bkt[pos]; }
    aptr[p] = Ab + arow * K + scsw;
  }
#pragma unroll
  for (int p = 0; p < 2; ++p) {
    size_t nrow = (size_t)(nt * BN + srow + p * 32);
    bptr[p] = Bb + nrow * K + scsw;
  }

  f32x4 acc[2][4];
#pragma unroll
  for (int i = 0; i < 2; ++i)
#pragma unroll
    for (int j = 0; j < 4; ++j) acc[i][j] = f32x4{0.f, 0.f, 0.f, 0.f};

  const int fr = lane & 15, fs = lane >> 4;
  const int csA = fr & 7;

  for (int kt = 0; kt < K; kt += BK) {
#pragma unroll
    for (int p = 0; p < 4; ++p)
      gload16(aptr[p] + kt, &lA[(srow + 32 * p) * BK + sc16 * 8]);
#pragma unroll
    for (int p = 0; p < 2; ++p)
      gload16(bptr[p] + kt, &lB[(srow + 32 * p) * BK + sc16 * 8]);
    __syncthreads();
#pragma unroll
    for (int kk = 0; kk < 2; ++kk) {
      const int c = ((kk * 4 + fs) ^ csA) * 8;
      short8 af[2];
#pragma unroll
      for (int mi = 0; mi < 2; ++mi)
        af[mi] = *reinterpret_cast<const short8*>(&lA[(wid * 32 + mi * 16 + fr) * BK + c]);
#pragma unroll
      for (int ni = 0; ni < 4; ++ni) {
        short8 bf = *reinterpret_cast<const short8*>(&lB[(ni * 16 + fr) * BK + c]);
#pragma unroll
        for (int mi = 0; mi < 2; ++mi)
          acc[mi][ni] = __builtin_amdgcn_mfma_f32_16x16x32_bf16(af[mi], bf, acc[mi][ni], 0, 0, 0);
      }
    }
    __syncthreads();
  }

  const float* bp = sh ? bs2 : be2 + (size_t)e * DIM;
#pragma unroll
  for (int mi = 0; mi < 2; ++mi) {
#pragma unroll
    for (int j = 0; j < 4; ++j) {
      int p = mt * BM + wid * 32 + mi * 16 + fs * 4 + j;
      if (p >= M) continue;
      int trow; float wgt;
      if (sh) { trow = p; wgt = 1.0f; }
      else { int slot = bkt[p]; trow = slot >> 1; wgt = tokw[slot]; }
      float* orow = out + (size_t)trow * DIM;
#pragma unroll
      for (int ni = 0; ni < 4; ++ni) {
        int gcol = nt * BN + ni * 16 + fr;
        atomicAdd(&orow[gcol], (acc[mi][ni][j] + bp[gcol]) * wgt);
      }
    }
  }
}

extern "C" void kernel_launch(void* const* d_in, const int* in_sizes, int n_in,
                              void* d_out, int out_size, void* d_ws, size_t ws_size,
                              hipStream_t stream) {
  const float* x   = (const float*)d_in[0];
  const float* gw  = (const float*)d_in[1];
  const float* gb  = (const float*)d_in[2];
  const float* We1 = (const float*)d_in[3];
  const float* be1 = (const float*)d_in[4];
  const float* We2 = (const float*)d_in[5];
  const float* be2 = (const float*)d_in[6];
  const float* We3 = (const float*)d_in[7];
  const float* be3 = (const float*)d_in[8];
  const float* ws1 = (const float*)d_in[9];
  const float* bs1 = (const float*)d_in[10];
  const float* ws2 = (const float*)d_in[11];
  const float* bs2 = (const float*)d_in[12];
  const float* ws3 = (const float*)d_in[13];
  const float* bs3 = (const float*)d_in[14];
  float* out = (float*)d_out;

  // workspace carve (~67 MB)
  char* w = (char*)d_ws;
  int*    counts = (int*)w;    w += 256;
  int*    bucket = (int*)w;    w += (size_t)NEXP * CAP * 4;
  float*  tokw   = (float*)w;  w += (size_t)2 * T_TOK * 4;
  u16*    xb     = (u16*)w;    w += (size_t)T_TOK * DIM * 2;
  u16*    w1t    = (u16*)w;    w += (size_t)NEXP * INTER * DIM * 2;
  u16*    w3t    = (u16*)w;    w += (size_t)NEXP * INTER * DIM * 2;
  u16*    w2t    = (u16*)w;    w += (size_t)NEXP * DIM * INTER * 2;
  u16*    s1t    = (u16*)w;    w += (size_t)NSH * DIM * 2;
  u16*    s3t    = (u16*)w;    w += (size_t)NSH * DIM * 2;
  u16*    s2t    = (u16*)w;    w += (size_t)DIM * NSH * 2;
  u16*    hr     = (u16*)w;    w += (size_t)2 * T_TOK * INTER * 2;
  u16*    hs     = (u16*)w;    w += (size_t)T_TOK * NSH * 2;

  hipMemsetAsync(counts, 0, 64, stream);
  hipMemsetAsync(out, 0, (size_t)T_TOK * DIM * 4, stream);

  TrJobs J;
  int base = 0;
  auto addJob = [&](int idx, const float* s, u16* d, int R, int C, int nb) {
    J.j[idx] = TrJob{s, d, R, C, base};
    base += nb * (R / 32) * (C / 32);
  };
  addJob(0, We1, w1t, DIM, INTER, NEXP);
  addJob(1, We3, w3t, DIM, INTER, NEXP);
  addJob(2, We2, w2t, INTER, DIM, NEXP);
  addJob(3, ws1, s1t, DIM, NSH, 1);
  addJob(4, ws3, s3t, DIM, NSH, 1);
  addJob(5, ws2, s2t, NSH, DIM, 1);
  k_tr_all<<<base, dim3(32, 8), 0, stream>>>(J);

  k_gate2<<<T_TOK / 16, 512, 0, stream>>>(x, gw, gb, xb, counts, bucket, tokw);

  // phase A: all first-layer SwiGLU GEMMs (z=0 shared, z=1..16 routed)
  k_g1<<<dim3(NSH / BN, 32, NEXP + 1), 256, 0, stream>>>(
      xb, w1t, w3t, s1t, s3t, be1, be3, bs1, bs3, hr, hs, counts, bucket);
  // phase B: all second-layer GEMMs, atomic accumulate into out
  k_g2<<<dim3(DIM / BN, 32, NEXP + 1), 256, 0, stream>>>(
      hr, hs, w2t, s2t, be2, bs2, out, tokw, counts, bucket);
}